// Round 11
// baseline (185.051 us; speedup 1.0000x reference)
//
#include <hip/hip_runtime.h>

// Problem constants
constexpr int Bn = 2;
constexpr int Sn = 2048;
constexpr int En = 512;
constexpr int Hn = 8;
constexpr int Dn = 64;
constexpr int Mn = Bn * Sn;              // 4096 rows

typedef short bf8 __attribute__((ext_vector_type(8)));
typedef float f32x4 __attribute__((ext_vector_type(4)));

// element counts (ushort units) for the bf16 workspace region
constexpr size_t XY = (size_t)Mn * En;          // 2,097,152  x planes
constexpr size_t WT = (size_t)3 * En * En;      //   786,432  Wqkv transposed planes
constexpr size_t WP = (size_t)En * En;          //   262,144  Wp planes
constexpr size_t PL = (size_t)Bn * Hn * Sn * Dn;// 2,097,152  q/k/v planes

__device__ __forceinline__ unsigned short f2bf(float f) {
    unsigned int u = __float_as_uint(f);
    unsigned int r = 0x7FFFu + ((u >> 16) & 1u);
    return (unsigned short)((u + r) >> 16);
}
__device__ __forceinline__ float bf2f(unsigned short u) {
    return __uint_as_float(((unsigned int)u) << 16);
}
__device__ __forceinline__ void split2(float f, unsigned short& hi, unsigned short& lo) {
    hi = f2bf(f);
    lo = f2bf(f - bf2f(hi));
}

// ---------------------------------------------------------------------------
// Prep (fused): blocks [0,1024) presplit x; [1024,1152) presplit Wp;
// [1152,1344) transpose+split Wq/Wk/Wv -> Wt[n][k]. (unchanged)
// ---------------------------------------------------------------------------
__global__ __launch_bounds__(256)
void prep(const float* __restrict__ x, const float* __restrict__ Wp,
          const float* __restrict__ Wq, const float* __restrict__ Wk,
          const float* __restrict__ Wv,
          unsigned short* __restrict__ xh, unsigned short* __restrict__ xl,
          unsigned short* __restrict__ Wph, unsigned short* __restrict__ Wpl,
          unsigned short* __restrict__ Wth, unsigned short* __restrict__ Wtl)
{
    __shared__ float t[64][65];
    const int bid = blockIdx.x;
    const int tid = threadIdx.x;

    if (bid < 1152) {
        const float* src = (bid < 1024) ? x : Wp;
        unsigned short* hp = (bid < 1024) ? xh : Wph;
        unsigned short* lp = (bid < 1024) ? xl : Wpl;
        const int blk = (bid < 1024) ? bid : (bid - 1024);
        const size_t base = ((size_t)blk * 256 + tid) * 8;
        float a[8];
        *(float4*)&a[0] = *(const float4*)(src + base);
        *(float4*)&a[4] = *(const float4*)(src + base + 4);
        unsigned short h[8], l[8];
        #pragma unroll
        for (int j = 0; j < 8; ++j) split2(a[j], h[j], l[j]);
        *(bf8*)(hp + base) = *(bf8*)&h[0];
        *(bf8*)(lp + base) = *(bf8*)&l[0];
        return;
    }

    const int idx = bid - 1152;           // 0..191
    const int ph = idx >> 3;              // 0..23
    const int proj = ph >> 3, h = ph & 7;
    const int e0 = (idx & 7) * 64;
    const float* W = (proj == 0) ? Wq : (proj == 1) ? Wk : Wv;
    const float* src = W + (size_t)h * En * Dn + (size_t)e0 * Dn;

    const int er = tid >> 2, cg = (tid & 3) * 16;
    #pragma unroll
    for (int c = 0; c < 4; ++c) {
        float4 v = *(const float4*)(src + (size_t)er * Dn + cg + 4 * c);
        t[er][cg + 4 * c + 0] = v.x;
        t[er][cg + 4 * c + 1] = v.y;
        t[er][cg + 4 * c + 2] = v.z;
        t[er][cg + 4 * c + 3] = v.w;
    }
    __syncthreads();

    const int d = tid >> 2, jg = (tid & 3) * 16;
    unsigned short h16[16], l16[16];
    #pragma unroll
    for (int j = 0; j < 16; ++j) split2(t[jg + j][d], h16[j], l16[j]);
    const size_t n = (size_t)proj * 512 + h * 64 + d;
    unsigned short* dh = Wth + n * En + e0 + jg;
    unsigned short* dl = Wtl + n * En + e0 + jg;
    *(bf8*)dh       = *(bf8*)&h16[0];
    *(bf8*)(dh + 8) = *(bf8*)&h16[8];
    *(bf8*)dl       = *(bf8*)&l16[0];
    *(bf8*)(dl + 8) = *(bf8*)&l16[8];
}

// ---------------------------------------------------------------------------
// Kernel 1 (v5 = R9-exact): fused QKV projection, 128x64 tiles (one head per
// block). Grid (32, 24) = 768 blocks -> 3 blocks/CU. LDS 30,720 B.
// ---------------------------------------------------------------------------
__global__ __launch_bounds__(256)
void qkv_gemm(const unsigned short* __restrict__ xh,
              const unsigned short* __restrict__ xl,
              const unsigned short* __restrict__ Wth,
              const unsigned short* __restrict__ Wtl,
              unsigned short* __restrict__ qh_g,
              unsigned short* __restrict__ ql_g,
              unsigned short* __restrict__ kh_g,
              unsigned short* __restrict__ kl_g,
              unsigned short* __restrict__ vT_g)
{
    __shared__ __align__(16) unsigned char smraw[30720];
    unsigned short (*Ah)[40] = (unsigned short(*)[40])(smraw);          // 128 x 40
    unsigned short (*Al)[40] = (unsigned short(*)[40])(smraw + 10240);
    unsigned short (*Bh)[40] = (unsigned short(*)[40])(smraw + 20480);  // 64 x 40
    unsigned short (*Bl)[40] = (unsigned short(*)[40])(smraw + 25600);
    float (*Cf)[68] = (float(*)[68])(smraw);    // 64 x 68 fp32 = 17,408 B

    const int tid = threadIdx.x;
    const int m0 = blockIdx.x * 128;
    const int ny = blockIdx.y;            // 0..23
    const int proj = ny >> 3, h = ny & 7;

    const int wave = tid >> 6, lane = tid & 63;
    const int wm = (wave >> 1) * 64, wn = (wave & 1) * 32;
    const int lm = lane & 15, quad = lane >> 4;

    const int am = tid >> 1;              // 0..127
    const int aks = (tid & 1) * 16;
    const unsigned short* arh = xh + (size_t)(m0 + am) * En + aks;
    const unsigned short* arl = xl + (size_t)(m0 + am) * En + aks;

    const int bn = tid >> 2;              // 0..63
    const int bks = (tid & 3) * 8;
    const unsigned short* brh = Wth + (size_t)(ny * 64 + bn) * En + bks;
    const unsigned short* brl = Wtl + (size_t)(ny * 64 + bn) * En + bks;

    f32x4 acc[4][2];
    #pragma unroll
    for (int i = 0; i < 4; ++i)
        #pragma unroll
        for (int j = 0; j < 2; ++j) acc[i][j] = (f32x4){0.f, 0.f, 0.f, 0.f};

    for (int k0 = 0; k0 < En; k0 += 32) {
        *(bf8*)&Ah[am][aks]     = *(const bf8*)(arh + k0);
        *(bf8*)&Ah[am][aks + 8] = *(const bf8*)(arh + k0 + 8);
        *(bf8*)&Al[am][aks]     = *(const bf8*)(arl + k0);
        *(bf8*)&Al[am][aks + 8] = *(const bf8*)(arl + k0 + 8);
        *(bf8*)&Bh[bn][bks]     = *(const bf8*)(brh + k0);
        *(bf8*)&Bl[bn][bks]     = *(const bf8*)(brl + k0);
        __syncthreads();

        bf8 a_h[4], a_l[4], b_h[2], b_l[2];
        #pragma unroll
        for (int mi = 0; mi < 4; ++mi) {
            a_h[mi] = *(const bf8*)&Ah[wm + mi * 16 + lm][quad * 8];
            a_l[mi] = *(const bf8*)&Al[wm + mi * 16 + lm][quad * 8];
        }
        #pragma unroll
        for (int ni = 0; ni < 2; ++ni) {
            b_h[ni] = *(const bf8*)&Bh[wn + ni * 16 + lm][quad * 8];
            b_l[ni] = *(const bf8*)&Bl[wn + ni * 16 + lm][quad * 8];
        }
        #pragma unroll
        for (int mi = 0; mi < 4; ++mi)
            #pragma unroll
            for (int ni = 0; ni < 2; ++ni) {
                acc[mi][ni] = __builtin_amdgcn_mfma_f32_16x16x32_bf16(a_h[mi], b_h[ni], acc[mi][ni], 0, 0, 0);
                acc[mi][ni] = __builtin_amdgcn_mfma_f32_16x16x32_bf16(a_h[mi], b_l[ni], acc[mi][ni], 0, 0, 0);
                acc[mi][ni] = __builtin_amdgcn_mfma_f32_16x16x32_bf16(a_l[mi], b_h[ni], acc[mi][ni], 0, 0, 0);
            }
        __syncthreads();
    }

    if (proj < 2) {
        unsigned short* hp = (proj == 0) ? qh_g : kh_g;
        unsigned short* lp = (proj == 0) ? ql_g : kl_g;
        #pragma unroll
        for (int p = 0; p < 2; ++p) {
            if ((wave >> 1) == p) {
                #pragma unroll
                for (int mi = 0; mi < 4; ++mi)
                    #pragma unroll
                    for (int ni = 0; ni < 2; ++ni)
                        #pragma unroll
                        for (int r = 0; r < 4; ++r)
                            Cf[mi * 16 + quad * 4 + r][wn + ni * 16 + lm] = acc[mi][ni][r];
            }
            __syncthreads();
            {
                const int lr = tid & 63;
                const int cg = (tid >> 6) * 16;   // wave-uniform d-chunk
                const int m = m0 + p * 64 + lr;
                const int b = m >> 11, s = m & 2047;
                unsigned short hi[16], lo[16];
                #pragma unroll
                for (int j4 = 0; j4 < 4; ++j4) {
                    float4 v = *(const float4*)&Cf[lr][cg + 4 * j4];
                    split2(v.x, hi[4 * j4 + 0], lo[4 * j4 + 0]);
                    split2(v.y, hi[4 * j4 + 1], lo[4 * j4 + 1]);
                    split2(v.z, hi[4 * j4 + 2], lo[4 * j4 + 2]);
                    split2(v.w, hi[4 * j4 + 3], lo[4 * j4 + 3]);
                }
                const size_t base = (((size_t)(b * Hn + h) * Sn + s) * Dn) + cg;
                *(bf8*)(hp + base)     = *(bf8*)&hi[0];
                *(bf8*)(hp + base + 8) = *(bf8*)&hi[8];
                *(bf8*)(lp + base)     = *(bf8*)&lo[0];
                *(bf8*)(lp + base + 8) = *(bf8*)&lo[8];
            }
            __syncthreads();
        }
    } else {
        #pragma unroll
        for (int mi = 0; mi < 4; ++mi) {
            const int s0 = m0 + wm + mi * 16 + quad * 4;
            const int b = s0 >> 11, s = s0 & 2047;
            #pragma unroll
            for (int ni = 0; ni < 2; ++ni) {
                const int d = wn + ni * 16 + lm;
                ushort4 pk;
                pk.x = f2bf(acc[mi][ni][0]);
                pk.y = f2bf(acc[mi][ni][1]);
                pk.z = f2bf(acc[mi][ni][2]);
                pk.w = f2bf(acc[mi][ni][3]);
                *(ushort4*)(vT_g + ((size_t)(b * Hn + h) * Dn + d) * Sn + s) = pk;
            }
        }
    }
}

// ---------------------------------------------------------------------------
// Kernel 2 (v6): MFMA flash attention, 4-way split-t.
// 2048 blocks; block j of (bh,qt) covers K-tiles [((qt+1)j)/4, ((qt+1)(j+1))/4).
// Longest block = 8 tiles (was 17). Partials to 4 Op planes + ml.
// ---------------------------------------------------------------------------
__global__ __launch_bounds__(256)
void attn(const unsigned short* __restrict__ qh_g,
          const unsigned short* __restrict__ ql_g,
          const unsigned short* __restrict__ kh_g,
          const unsigned short* __restrict__ kl_g,
          const unsigned short* __restrict__ vT_g,
          unsigned short* __restrict__ Op0,
          unsigned short* __restrict__ Op1,
          unsigned short* __restrict__ Op2,
          unsigned short* __restrict__ Op3,
          float* __restrict__ ml)
{
    extern __shared__ unsigned short sm[];
    unsigned short (*khs)[72] = (unsigned short(*)[72])(sm);          // [t][d] hi
    unsigned short (*kls)[72] = (unsigned short(*)[72])(sm + 4608);   // [t][d] lo
    unsigned short (*vTs)[72] = (unsigned short(*)[72])(sm + 9216);   // [d][t]
    unsigned short (*pts)[72] = (unsigned short(*)[72])(sm + 13824);  // [q][t]
    float* alf = (float*)(sm + 18432);                                // [64]

    const int bidx = blockIdx.x;
    const int j4 = bidx >> 9;             // split index 0..3
    const int r_ = bidx & 511;
    const int a_ = r_ >> 4, bh = r_ & 15;
    const int qt = (j4 & 1) ? (31 - a_) : a_;   // direction alternation
    const int its = ((qt + 1) * j4) >> 2;
    const int ite = ((qt + 1) * (j4 + 1)) >> 2;
    const int pslot = j4 * 512 + bh * 32 + qt;
    unsigned short* Opj = (j4 == 0) ? Op0 : (j4 == 1) ? Op1 : (j4 == 2) ? Op2 : Op3;

    const int tid = threadIdx.x;
    const int wave = tid >> 6, lane = tid & 63;
    const int quad = lane >> 4, lq = lane & 15;

    const unsigned short* khb = kh_g + (size_t)bh * Sn * Dn;
    const unsigned short* klb = kl_g + (size_t)bh * Sn * Dn;
    const unsigned short* vTb = vT_g + (size_t)bh * Dn * Sn;

    bf8 qfh[2], qfl[2];
    {
        const size_t qoff = ((size_t)bh * Sn + (size_t)qt * 64 + wave * 16 + lq) * Dn;
        #pragma unroll
        for (int c = 0; c < 2; ++c) {
            qfh[c] = *(const bf8*)(qh_g + qoff + c * 32 + quad * 8);
            qfl[c] = *(const bf8*)(ql_g + qoff + c * 32 + quad * 8);
        }
    }

    f32x4 accO[4];
    #pragma unroll
    for (int nj = 0; nj < 4; ++nj) accO[nj] = (f32x4){0.f, 0.f, 0.f, 0.f};
    float m = -1e30f, l = 0.f;

    const int srow = tid & 63;
    const int sdg  = tid >> 6;

    bf8 pk0, pk1, pl0, pl1, pv0, pv1;
    if (its < ite) {
        const int t0 = its * 64;
        const unsigned short* kr = khb + (size_t)(t0 + srow) * Dn + sdg * 16;
        const unsigned short* lr = klb + (size_t)(t0 + srow) * Dn + sdg * 16;
        const unsigned short* vr = vTb + (size_t)srow * Sn + t0 + sdg * 16;
        pk0 = *(const bf8*)(kr);  pk1 = *(const bf8*)(kr + 8);
        pl0 = *(const bf8*)(lr);  pl1 = *(const bf8*)(lr + 8);
        pv0 = *(const bf8*)(vr);  pv1 = *(const bf8*)(vr + 8);
    }

    for (int it = its; it < ite; ++it) {
        __syncthreads();
        *(bf8*)&khs[srow][sdg * 16]     = pk0;
        *(bf8*)&khs[srow][sdg * 16 + 8] = pk1;
        *(bf8*)&kls[srow][sdg * 16]     = pl0;
        *(bf8*)&kls[srow][sdg * 16 + 8] = pl1;
        *(bf8*)&vTs[srow][sdg * 16]     = pv0;
        *(bf8*)&vTs[srow][sdg * 16 + 8] = pv1;
        __syncthreads();

        if (it + 1 < ite) {
            const int t1 = (it + 1) * 64;
            const unsigned short* kr = khb + (size_t)(t1 + srow) * Dn + sdg * 16;
            const unsigned short* lr = klb + (size_t)(t1 + srow) * Dn + sdg * 16;
            const unsigned short* vr = vTb + (size_t)srow * Sn + t1 + sdg * 16;
            pk0 = *(const bf8*)(kr);  pk1 = *(const bf8*)(kr + 8);
            pl0 = *(const bf8*)(lr);  pl1 = *(const bf8*)(lr + 8);
            pv0 = *(const bf8*)(vr);  pv1 = *(const bf8*)(vr + 8);
        }

        f32x4 accS[4];
        #pragma unroll
        for (int mi = 0; mi < 4; ++mi) accS[mi] = (f32x4){0.f, 0.f, 0.f, 0.f};
        #pragma unroll
        for (int mi = 0; mi < 4; ++mi) {
            #pragma unroll
            for (int c = 0; c < 2; ++c) {
                bf8 ah = *(const bf8*)&khs[mi * 16 + lq][c * 32 + quad * 8];
                bf8 al = *(const bf8*)&kls[mi * 16 + lq][c * 32 + quad * 8];
                accS[mi] = __builtin_amdgcn_mfma_f32_16x16x32_bf16(ah, qfh[c], accS[mi], 0, 0, 0);
                accS[mi] = __builtin_amdgcn_mfma_f32_16x16x32_bf16(ah, qfl[c], accS[mi], 0, 0, 0);
                accS[mi] = __builtin_amdgcn_mfma_f32_16x16x32_bf16(al, qfh[c], accS[mi], 0, 0, 0);
            }
        }

        if (it == qt) {
            const int qrel = wave * 16 + lq;
            #pragma unroll
            for (int mi = 0; mi < 4; ++mi)
                #pragma unroll
                for (int r = 0; r < 4; ++r)
                    if (mi * 16 + quad * 4 + r > qrel) accS[mi][r] = -INFINITY;
        }

        float mt = -INFINITY;
        #pragma unroll
        for (int mi = 0; mi < 4; ++mi)
            #pragma unroll
            for (int r = 0; r < 4; ++r) mt = fmaxf(mt, accS[mi][r]);
        mt = fmaxf(mt, __shfl_xor(mt, 16));
        mt = fmaxf(mt, __shfl_xor(mt, 32));
        const float mnew = fmaxf(m, mt);
        const float alpha = __expf(m - mnew);
        float ls = 0.f;
        #pragma unroll
        for (int mi = 0; mi < 4; ++mi)
            #pragma unroll
            for (int r = 0; r < 4; ++r) {
                const float p = __expf(accS[mi][r] - mnew);
                accS[mi][r] = p;
                ls += p;
            }
        ls += __shfl_xor(ls, 16);
        ls += __shfl_xor(ls, 32);
        l = l * alpha + ls;
        m = mnew;

        #pragma unroll
        for (int mi = 0; mi < 4; ++mi) {
            ushort4 pk;
            pk.x = f2bf(accS[mi][0]);
            pk.y = f2bf(accS[mi][1]);
            pk.z = f2bf(accS[mi][2]);
            pk.w = f2bf(accS[mi][3]);
            *(ushort4*)&pts[wave * 16 + lq][mi * 16 + quad * 4] = pk;
        }
        if (quad == 0) alf[wave * 16 + lq] = alpha;

        {
            float4 al4 = *(const float4*)&alf[wave * 16 + quad * 4];
            #pragma unroll
            for (int nj = 0; nj < 4; ++nj) {
                accO[nj][0] *= al4.x;
                accO[nj][1] *= al4.y;
                accO[nj][2] *= al4.z;
                accO[nj][3] *= al4.w;
            }
            #pragma unroll
            for (int c = 0; c < 2; ++c) {
                bf8 pf = *(const bf8*)&pts[wave * 16 + lq][c * 32 + quad * 8];
                #pragma unroll
                for (int nj = 0; nj < 4; ++nj) {
                    bf8 vf = *(const bf8*)&vTs[nj * 16 + lq][c * 32 + quad * 8];
                    accO[nj] = __builtin_amdgcn_mfma_f32_16x16x32_bf16(pf, vf, accO[nj], 0, 0, 0);
                }
            }
        }
    }

    if (quad == 0) {
        const size_t mi_ = ((size_t)pslot * 64 + wave * 16 + lq) * 2;
        ml[mi_]     = m;
        ml[mi_ + 1] = l;
    }
    #pragma unroll
    for (int r = 0; r < 4; ++r) {
        const int q = wave * 16 + quad * 4 + r;
        unsigned short* dst = Opj + (((size_t)(bh * 32 + qt)) * 64 + q) * 64;
        #pragma unroll
        for (int nj = 0; nj < 4; ++nj)
            dst[nj * 16 + lq] = f2bf(accO[nj][r]);
    }
}

// ---------------------------------------------------------------------------
// Kernel 3 (v7): fused 4-way combine + out-projection + residual, split-K=2.
// R9 loop structure (no register prefetch). Grid (64, 4, 2) = 512 blocks.
// ---------------------------------------------------------------------------
__global__ __launch_bounds__(256)
void out_gemm(const unsigned short* __restrict__ Op0,
              const unsigned short* __restrict__ Op1,
              const unsigned short* __restrict__ Op2,
              const unsigned short* __restrict__ Op3,
              const float* __restrict__ ml,
              const unsigned short* __restrict__ Wph,
              const unsigned short* __restrict__ Wpl,
              const float* __restrict__ bp,
              const float* __restrict__ x,
              float* __restrict__ outp,
              float* __restrict__ outp2)
{
    __shared__ unsigned short Ah[64][40], Al[64][40];
    __shared__ unsigned short Bh[128][40], Bl[128][40];

    const int tid = threadIdx.x;
    const int m0 = blockIdx.x * 64;
    const int n0 = blockIdx.y * 128;
    const int kz = blockIdx.z;
    const int kbeg = kz * 256, kend = kbeg + 256;

    const int wave = tid >> 6, lane = tid & 63;
    const int wm = (wave >> 1) * 32, wn = (wave & 1) * 64;
    const int lm = lane & 15, quad = lane >> 4;

    const int am = tid >> 2;
    const int aks = (tid & 3) * 8;
    const int m_row = m0 + am;
    const int b_row = m_row >> 11, s_row = m_row & 2047;
    const int qt = s_row >> 6, qq = s_row & 63;

    // per-(head, partial) combine weights for this row
    float cw[8][4];
    #pragma unroll
    for (int h = 0; h < 8; ++h) {
        const int slot = (b_row * 8 + h) * 32 + qt;
        float mj[4], lj[4];
        #pragma unroll
        for (int j = 0; j < 4; ++j) {
            const size_t base = (((size_t)(j * 512 + slot)) * 64 + qq) * 2;
            mj[j] = ml[base];
            lj[j] = ml[base + 1];
        }
        float mn = fmaxf(fmaxf(mj[0], mj[1]), fmaxf(mj[2], mj[3]));
        float aj[4], denom = 0.f;
        #pragma unroll
        for (int j = 0; j < 4; ++j) { aj[j] = __expf(mj[j] - mn); denom += aj[j] * lj[j]; }
        const float inv = 1.f / denom;
        #pragma unroll
        for (int j = 0; j < 4; ++j) cw[h][j] = aj[j] * inv;
    }

    const int bn = tid >> 1;
    const int bks = (tid & 1) * 16;
    const unsigned short* brh = Wph + (size_t)(n0 + bn) * En + bks;
    const unsigned short* brl = Wpl + (size_t)(n0 + bn) * En + bks;

    f32x4 acc[2][4];
    #pragma unroll
    for (int i = 0; i < 2; ++i)
        #pragma unroll
        for (int j = 0; j < 4; ++j) acc[i][j] = (f32x4){0.f, 0.f, 0.f, 0.f};

    for (int k0 = kbeg; k0 < kend; k0 += 32) {
        {
            const int e0 = k0 + aks;          // 8 elems, single head
            const int h = 7 - (e0 >> 6);
            const int d = e0 & 63;
            const size_t po = (((size_t)((b_row * 8 + h) * 32 + qt)) * 64 + qq) * 64 + d;
            bf8 o0 = *(const bf8*)(Op0 + po);
            bf8 o1 = *(const bf8*)(Op1 + po);
            bf8 o2 = *(const bf8*)(Op2 + po);
            bf8 o3 = *(const bf8*)(Op3 + po);
            const float w0 = cw[h][0], w1 = cw[h][1], w2 = cw[h][2], w3 = cw[h][3];
            unsigned short hi[8], lo[8];
            #pragma unroll
            for (int j = 0; j < 8; ++j) {
                const float v = w0 * bf2f((unsigned short)o0[j]) +
                                w1 * bf2f((unsigned short)o1[j]) +
                                w2 * bf2f((unsigned short)o2[j]) +
                                w3 * bf2f((unsigned short)o3[j]);
                split2(v, hi[j], lo[j]);
            }
            *(bf8*)&Ah[am][aks] = *(bf8*)&hi[0];
            *(bf8*)&Al[am][aks] = *(bf8*)&lo[0];
        }
        *(bf8*)&Bh[bn][bks]     = *(const bf8*)(brh + k0);
        *(bf8*)&Bh[bn][bks + 8] = *(const bf8*)(brh + k0 + 8);
        *(bf8*)&Bl[bn][bks]     = *(const bf8*)(brl + k0);
        *(bf8*)&Bl[bn][bks + 8] = *(const bf8*)(brl + k0 + 8);
        __syncthreads();

        bf8 a_h[2], a_l[2], b_h[4], b_l[4];
        #pragma unroll
        for (int mi = 0; mi < 2; ++mi) {
            a_h[mi] = *(const bf8*)&Ah[wm + mi * 16 + lm][quad * 8];
            a_l[mi] = *(const bf8*)&Al[wm + mi * 16 + lm][quad * 8];
        }
        #pragma unroll
        for (int ni = 0; ni < 4; ++ni) {
            b_h[ni] = *(const bf8*)&Bh[wn + ni * 16 + lm][quad * 8];
            b_l[ni] = *(const bf8*)&Bl[wn + ni * 16 + lm][quad * 8];
        }
        #pragma unroll
        for (int mi = 0; mi < 2; ++mi)
            #pragma unroll
            for (int ni = 0; ni < 4; ++ni) {
                acc[mi][ni] = __builtin_amdgcn_mfma_f32_16x16x32_bf16(a_h[mi], b_h[ni], acc[mi][ni], 0, 0, 0);
                acc[mi][ni] = __builtin_amdgcn_mfma_f32_16x16x32_bf16(a_h[mi], b_l[ni], acc[mi][ni], 0, 0, 0);
                acc[mi][ni] = __builtin_amdgcn_mfma_f32_16x16x32_bf16(a_l[mi], b_h[ni], acc[mi][ni], 0, 0, 0);
            }
        __syncthreads();
    }

    float* dst = kz ? outp2 : outp;
    #pragma unroll
    for (int mi = 0; mi < 2; ++mi) {
        #pragma unroll
        for (int r = 0; r < 4; ++r) {
            const int m = m0 + wm + mi * 16 + quad * 4 + r;
            #pragma unroll
            for (int ni = 0; ni < 4; ++ni) {
                const int n = n0 + wn + ni * 16 + lm;
                const size_t idx = (size_t)m * En + n;
                const float extra = kz ? 0.f : (bp[n] + x[idx]);
                dst[idx] = acc[mi][ni][r] + extra;
            }
        }
    }
}

// ---------------------------------------------------------------------------
// Kernel 4 (v3): LayerNorm over (outp + outp2), 1 wave per row. (unchanged)
// ---------------------------------------------------------------------------
__global__ __launch_bounds__(256)
void ln_kernel(const float* __restrict__ outp,
               const float* __restrict__ outp2,
               const float* __restrict__ gamma,
               const float* __restrict__ beta,
               float* __restrict__ y)
{
    const int row = blockIdx.x * 4 + (threadIdx.x >> 6);
    const int lane = threadIdx.x & 63;
    const size_t off = (size_t)row * En + lane * 8;

    float a[8], b2[8];
    *(float4*)&a[0] = *(const float4*)(outp + off);
    *(float4*)&a[4] = *(const float4*)(outp + off + 4);
    *(float4*)&b2[0] = *(const float4*)(outp2 + off);
    *(float4*)&b2[4] = *(const float4*)(outp2 + off + 4);
    #pragma unroll
    for (int j = 0; j < 8; ++j) a[j] += b2[j];

    float sum = 0.f, sq = 0.f;
    #pragma unroll
    for (int j = 0; j < 8; ++j) { sum += a[j]; sq += a[j] * a[j]; }
    #pragma unroll
    for (int off_ = 1; off_ < 64; off_ <<= 1) {
        sum += __shfl_xor(sum, off_);
        sq  += __shfl_xor(sq, off_);
    }
    const float mu = sum * (1.f / 512.f);
    const float var = sq * (1.f / 512.f) - mu * mu;
    const float rs = rsqrtf(var + 1e-5f);

    const float* g = gamma + lane * 8;
    const float* be = beta + lane * 8;
    float o[8];
    #pragma unroll
    for (int j = 0; j < 8; ++j)
        o[j] = (a[j] - mu) * rs * g[j] + be[j];
    float* yr = y + off;
    *(float4*)(yr)     = *(float4*)&o[0];
    *(float4*)(yr + 4) = *(float4*)&o[4];
}

// ---------------------------------------------------------------------------
extern "C" void kernel_launch(void* const* d_in, const int* in_sizes, int n_in,
                              void* d_out, int out_size, void* d_ws, size_t ws_size,
                              hipStream_t stream)
{
    const float* x     = (const float*)d_in[0];
    const float* Wq    = (const float*)d_in[1];
    const float* Wk    = (const float*)d_in[2];
    const float* Wv    = (const float*)d_in[3];
    const float* Wp    = (const float*)d_in[4];
    const float* bp    = (const float*)d_in[5];
    const float* gamma = (const float*)d_in[6];
    const float* beta  = (const float*)d_in[7];
    // d_in[8] = mask (int32 tril) — causal, applied analytically.

    float* ws = (float*)d_ws;
    // Workspace map (48 MB total):
    //   [ws, ws+XY)       : ml (262,144 floats) + Op2 (4 MB, at ws+262144)
    //   [ws+XY, ws+2XY)   : Op3 (4 MB at slot start; rest unused)
    //   bf16 region at ws+2XY: xh xl Wth Wtl Wph Wpl qh ql kh kl vT
    //   Op0=xh, Op1=xl (dead after qkv); outp->qh+ql, outp2->kh+kl (dead after attn)
    float* ml = ws;
    unsigned short* Op2 = (unsigned short*)(ws + 262144);
    unsigned short* Op3 = (unsigned short*)(ws + XY);
    unsigned short* bfb = (unsigned short*)(ws + 2 * XY);
    unsigned short* xh  = bfb;
    unsigned short* xl  = bfb + XY;
    unsigned short* Wth = bfb + 2 * XY;
    unsigned short* Wtl = Wth + WT;
    unsigned short* Wph = Wtl + WT;
    unsigned short* Wpl = Wph + WP;
    unsigned short* qh  = Wpl + WP;
    unsigned short* ql  = qh + PL;
    unsigned short* kh  = ql + PL;
    unsigned short* kl  = kh + PL;
    unsigned short* vT  = kl + PL;
    unsigned short* Op0 = xh;
    unsigned short* Op1 = xl;
    float* outp  = (float*)qh;
    float* outp2 = (float*)kh;

    const int attn_lds = 18432 * 2 + 256;        // 37,120 B
    hipFuncSetAttribute((const void*)attn,
                        hipFuncAttributeMaxDynamicSharedMemorySize, attn_lds);

    prep<<<dim3(1344), 256, 0, stream>>>(x, Wp, Wq, Wk, Wv,
                                         xh, xl, Wph, Wpl, Wth, Wtl);
    qkv_gemm<<<dim3(Mn / 128, 24), 256, 0, stream>>>(xh, xl, Wth, Wtl,
                                                     qh, ql, kh, kl, vT);
    attn<<<dim3(2048), 256, attn_lds, stream>>>(qh, ql, kh, kl, vT,
                                                Op0, Op1, Op2, Op3, ml);
    out_gemm<<<dim3(Mn / 64, En / 128, 2), 256, 0, stream>>>(Op0, Op1, Op2, Op3,
                                                             ml, Wph, Wpl,
                                                             bp, x, outp, outp2);
    ln_kernel<<<dim3(Mn / 4), 256, 0, stream>>>(outp, outp2, gamma, beta,
                                                (float*)d_out);
}

// Round 12
// 182.841 us; speedup vs baseline: 1.0121x; 1.0121x over previous
//
#include <hip/hip_runtime.h>

// Problem constants
constexpr int Bn = 2;
constexpr int Sn = 2048;
constexpr int En = 512;
constexpr int Hn = 8;
constexpr int Dn = 64;
constexpr int Mn = Bn * Sn;              // 4096 rows

typedef short bf8 __attribute__((ext_vector_type(8)));
typedef float f32x4 __attribute__((ext_vector_type(4)));

// element counts (ushort units) for the bf16 workspace region
constexpr size_t XY = (size_t)Mn * En;          // 2,097,152  x planes
constexpr size_t WT = (size_t)3 * En * En;      //   786,432  Wqkv transposed planes
constexpr size_t WP = (size_t)En * En;          //   262,144  Wp planes
constexpr size_t PL = (size_t)Bn * Hn * Sn * Dn;// 2,097,152  q/k/v planes

__device__ __forceinline__ unsigned short f2bf(float f) {
    unsigned int u = __float_as_uint(f);
    unsigned int r = 0x7FFFu + ((u >> 16) & 1u);
    return (unsigned short)((u + r) >> 16);
}
__device__ __forceinline__ float bf2f(unsigned short u) {
    return __uint_as_float(((unsigned int)u) << 16);
}
__device__ __forceinline__ void split2(float f, unsigned short& hi, unsigned short& lo) {
    hi = f2bf(f);
    lo = f2bf(f - bf2f(hi));
}

// ---------------------------------------------------------------------------
// Prep (fused): blocks [0,1024) presplit x; [1024,1152) presplit Wp;
// [1152,1344) transpose+split Wq/Wk/Wv -> Wt[n][k]. (unchanged)
// ---------------------------------------------------------------------------
__global__ __launch_bounds__(256)
void prep(const float* __restrict__ x, const float* __restrict__ Wp,
          const float* __restrict__ Wq, const float* __restrict__ Wk,
          const float* __restrict__ Wv,
          unsigned short* __restrict__ xh, unsigned short* __restrict__ xl,
          unsigned short* __restrict__ Wph, unsigned short* __restrict__ Wpl,
          unsigned short* __restrict__ Wth, unsigned short* __restrict__ Wtl)
{
    __shared__ float t[64][65];
    const int bid = blockIdx.x;
    const int tid = threadIdx.x;

    if (bid < 1152) {
        const float* src = (bid < 1024) ? x : Wp;
        unsigned short* hp = (bid < 1024) ? xh : Wph;
        unsigned short* lp = (bid < 1024) ? xl : Wpl;
        const int blk = (bid < 1024) ? bid : (bid - 1024);
        const size_t base = ((size_t)blk * 256 + tid) * 8;
        float a[8];
        *(float4*)&a[0] = *(const float4*)(src + base);
        *(float4*)&a[4] = *(const float4*)(src + base + 4);
        unsigned short h[8], l[8];
        #pragma unroll
        for (int j = 0; j < 8; ++j) split2(a[j], h[j], l[j]);
        *(bf8*)(hp + base) = *(bf8*)&h[0];
        *(bf8*)(lp + base) = *(bf8*)&l[0];
        return;
    }

    const int idx = bid - 1152;           // 0..191
    const int ph = idx >> 3;              // 0..23
    const int proj = ph >> 3, h = ph & 7;
    const int e0 = (idx & 7) * 64;
    const float* W = (proj == 0) ? Wq : (proj == 1) ? Wk : Wv;
    const float* src = W + (size_t)h * En * Dn + (size_t)e0 * Dn;

    const int er = tid >> 2, cg = (tid & 3) * 16;
    #pragma unroll
    for (int c = 0; c < 4; ++c) {
        float4 v = *(const float4*)(src + (size_t)er * Dn + cg + 4 * c);
        t[er][cg + 4 * c + 0] = v.x;
        t[er][cg + 4 * c + 1] = v.y;
        t[er][cg + 4 * c + 2] = v.z;
        t[er][cg + 4 * c + 3] = v.w;
    }
    __syncthreads();

    const int d = tid >> 2, jg = (tid & 3) * 16;
    unsigned short h16[16], l16[16];
    #pragma unroll
    for (int j = 0; j < 16; ++j) split2(t[jg + j][d], h16[j], l16[j]);
    const size_t n = (size_t)proj * 512 + h * 64 + d;
    unsigned short* dh = Wth + n * En + e0 + jg;
    unsigned short* dl = Wtl + n * En + e0 + jg;
    *(bf8*)dh       = *(bf8*)&h16[0];
    *(bf8*)(dh + 8) = *(bf8*)&h16[8];
    *(bf8*)dl       = *(bf8*)&l16[0];
    *(bf8*)(dl + 8) = *(bf8*)&l16[8];
}

// ---------------------------------------------------------------------------
// Kernel 1 (v7): fused QKV projection, 128x128 tiles, 512 threads (8 waves
// of 64x32 — per-wave code identical to v5). Halves x re-reads (12 n-passes
// vs 24). Grid (12, 32), x-fastest: same-m blocks temporally adjacent.
// LDS 40,960 B staging; epilogue via 64x132 fp32 Cf (aliased), 2 passes.
// ---------------------------------------------------------------------------
__global__ __launch_bounds__(512)
void qkv_gemm(const unsigned short* __restrict__ xh,
              const unsigned short* __restrict__ xl,
              const unsigned short* __restrict__ Wth,
              const unsigned short* __restrict__ Wtl,
              unsigned short* __restrict__ qh_g,
              unsigned short* __restrict__ ql_g,
              unsigned short* __restrict__ kh_g,
              unsigned short* __restrict__ kl_g,
              unsigned short* __restrict__ vT_g)
{
    __shared__ __align__(16) unsigned char smraw[40960];
    unsigned short (*Ah)[40] = (unsigned short(*)[40])(smraw);          // 128 x 40
    unsigned short (*Al)[40] = (unsigned short(*)[40])(smraw + 10240);
    unsigned short (*Bh)[40] = (unsigned short(*)[40])(smraw + 20480);  // 128 x 40
    unsigned short (*Bl)[40] = (unsigned short(*)[40])(smraw + 30720);
    float (*Cf)[132] = (float(*)[132])(smraw);  // 64 x 132 fp32 = 33,792 B

    const int tid = threadIdx.x;
    const int ny = blockIdx.x;            // 0..11 (128-wide n-tile)
    const int m0 = blockIdx.y * 128;
    const int proj = ny >> 2;             // 4 n-tiles per projection

    const int wave = tid >> 6, lane = tid & 63;
    const int wm = (wave & 1) * 64;       // m-half
    const int wn = (wave >> 1) * 32;      // n-quarter
    const int lm = lane & 15, quad = lane >> 4;

    const int am = tid >> 2;              // 0..127
    const int aks = (tid & 3) * 8;        // 0,8,16,24
    const unsigned short* arh = xh + (size_t)(m0 + am) * En + aks;
    const unsigned short* arl = xl + (size_t)(m0 + am) * En + aks;

    const int bn = tid >> 2;              // 0..127
    const int bks = (tid & 3) * 8;
    const unsigned short* brh = Wth + (size_t)(ny * 128 + bn) * En + bks;
    const unsigned short* brl = Wtl + (size_t)(ny * 128 + bn) * En + bks;

    f32x4 acc[4][2];
    #pragma unroll
    for (int i = 0; i < 4; ++i)
        #pragma unroll
        for (int j = 0; j < 2; ++j) acc[i][j] = (f32x4){0.f, 0.f, 0.f, 0.f};

    for (int k0 = 0; k0 < En; k0 += 32) {
        *(bf8*)&Ah[am][aks] = *(const bf8*)(arh + k0);
        *(bf8*)&Al[am][aks] = *(const bf8*)(arl + k0);
        *(bf8*)&Bh[bn][bks] = *(const bf8*)(brh + k0);
        *(bf8*)&Bl[bn][bks] = *(const bf8*)(brl + k0);
        __syncthreads();

        bf8 a_h[4], a_l[4], b_h[2], b_l[2];
        #pragma unroll
        for (int mi = 0; mi < 4; ++mi) {
            a_h[mi] = *(const bf8*)&Ah[wm + mi * 16 + lm][quad * 8];
            a_l[mi] = *(const bf8*)&Al[wm + mi * 16 + lm][quad * 8];
        }
        #pragma unroll
        for (int ni = 0; ni < 2; ++ni) {
            b_h[ni] = *(const bf8*)&Bh[wn + ni * 16 + lm][quad * 8];
            b_l[ni] = *(const bf8*)&Bl[wn + ni * 16 + lm][quad * 8];
        }
        #pragma unroll
        for (int mi = 0; mi < 4; ++mi)
            #pragma unroll
            for (int ni = 0; ni < 2; ++ni) {
                acc[mi][ni] = __builtin_amdgcn_mfma_f32_16x16x32_bf16(a_h[mi], b_h[ni], acc[mi][ni], 0, 0, 0);
                acc[mi][ni] = __builtin_amdgcn_mfma_f32_16x16x32_bf16(a_h[mi], b_l[ni], acc[mi][ni], 0, 0, 0);
                acc[mi][ni] = __builtin_amdgcn_mfma_f32_16x16x32_bf16(a_l[mi], b_h[ni], acc[mi][ni], 0, 0, 0);
            }
        __syncthreads();
    }

    if (proj < 2) {
        unsigned short* hp = (proj == 0) ? qh_g : kh_g;
        unsigned short* lp = (proj == 0) ? ql_g : kl_g;
        // two passes (m-halves) through the 64x132 fp32 transpose buffer
        #pragma unroll
        for (int p = 0; p < 2; ++p) {
            if ((wave & 1) == p) {
                #pragma unroll
                for (int mi = 0; mi < 4; ++mi)
                    #pragma unroll
                    for (int ni = 0; ni < 2; ++ni)
                        #pragma unroll
                        for (int r = 0; r < 4; ++r)
                            Cf[mi * 16 + quad * 4 + r][wn + ni * 16 + lm] = acc[mi][ni][r];
            }
            __syncthreads();
            {
                const int lr = tid & 63;
                const int cg = (tid >> 6) * 16;   // wave-uniform 16-wide chunk, 0..112
                const int m = m0 + p * 64 + lr;
                const int b = m >> 11, s = m & 2047;
                const int h = (ny & 3) * 2 + (cg >> 6);
                const int d = cg & 63;
                unsigned short hi[16], lo[16];
                #pragma unroll
                for (int j4 = 0; j4 < 4; ++j4) {
                    float4 v = *(const float4*)&Cf[lr][cg + 4 * j4];
                    split2(v.x, hi[4 * j4 + 0], lo[4 * j4 + 0]);
                    split2(v.y, hi[4 * j4 + 1], lo[4 * j4 + 1]);
                    split2(v.z, hi[4 * j4 + 2], lo[4 * j4 + 2]);
                    split2(v.w, hi[4 * j4 + 3], lo[4 * j4 + 3]);
                }
                const size_t base = (((size_t)(b * Hn + h) * Sn + s) * Dn) + d;
                *(bf8*)(hp + base)     = *(bf8*)&hi[0];
                *(bf8*)(hp + base + 8) = *(bf8*)&hi[8];
                *(bf8*)(lp + base)     = *(bf8*)&lo[0];
                *(bf8*)(lp + base + 8) = *(bf8*)&lo[8];
            }
            __syncthreads();
        }
    } else {
        // V: transposed bf16 store, pack 4 consecutive s per ushort4
        #pragma unroll
        for (int mi = 0; mi < 4; ++mi) {
            const int s0 = m0 + wm + mi * 16 + quad * 4;
            const int b = s0 >> 11, s = s0 & 2047;
            #pragma unroll
            for (int ni = 0; ni < 2; ++ni) {
                const int nl = wn + ni * 16 + lm;       // 0..127
                const int h = (ny & 3) * 2 + (nl >> 6);
                const int d = nl & 63;
                ushort4 pk;
                pk.x = f2bf(acc[mi][ni][0]);
                pk.y = f2bf(acc[mi][ni][1]);
                pk.z = f2bf(acc[mi][ni][2]);
                pk.w = f2bf(acc[mi][ni][3]);
                *(ushort4*)(vT_g + ((size_t)(b * Hn + h) * Dn + d) * Sn + s) = pk;
            }
        }
    }
}

// ---------------------------------------------------------------------------
// Kernel 2 (v5 = R9-exact): MFMA flash attention, 2-way split-t.
// ---------------------------------------------------------------------------
__global__ __launch_bounds__(256)
void attn(const unsigned short* __restrict__ qh_g,
          const unsigned short* __restrict__ ql_g,
          const unsigned short* __restrict__ kh_g,
          const unsigned short* __restrict__ kl_g,
          const unsigned short* __restrict__ vT_g,
          unsigned short* __restrict__ Op,
          float* __restrict__ ml)
{
    extern __shared__ unsigned short sm[];
    unsigned short (*khs)[72] = (unsigned short(*)[72])(sm);          // [t][d] hi
    unsigned short (*kls)[72] = (unsigned short(*)[72])(sm + 4608);   // [t][d] lo
    unsigned short (*vTs)[72] = (unsigned short(*)[72])(sm + 9216);   // [d][t]
    unsigned short (*pts)[72] = (unsigned short(*)[72])(sm + 13824);  // [q][t]
    float* alf = (float*)(sm + 18432);                                // [64]

    const int bidx = blockIdx.x;
    const int r_ = bidx & 255, quarter = bidx >> 8;
    const int a_ = r_ >> 4, bh = r_ & 15;
    const int qt = (quarter & 1) ? (31 - a_) : a_;
    const int hf = quarter >> 1;
    const int n0 = (qt + 2) >> 1;
    const int its = hf ? n0 : 0;
    const int ite = hf ? (qt + 1) : n0;
    const int pslot = hf * 512 + bh * 32 + qt;

    const int tid = threadIdx.x;
    const int wave = tid >> 6, lane = tid & 63;
    const int quad = lane >> 4, lq = lane & 15;

    const unsigned short* khb = kh_g + (size_t)bh * Sn * Dn;
    const unsigned short* klb = kl_g + (size_t)bh * Sn * Dn;
    const unsigned short* vTb = vT_g + (size_t)bh * Dn * Sn;

    bf8 qfh[2], qfl[2];
    {
        const size_t qoff = ((size_t)bh * Sn + (size_t)qt * 64 + wave * 16 + lq) * Dn;
        #pragma unroll
        for (int c = 0; c < 2; ++c) {
            qfh[c] = *(const bf8*)(qh_g + qoff + c * 32 + quad * 8);
            qfl[c] = *(const bf8*)(ql_g + qoff + c * 32 + quad * 8);
        }
    }

    f32x4 accO[4];
    #pragma unroll
    for (int nj = 0; nj < 4; ++nj) accO[nj] = (f32x4){0.f, 0.f, 0.f, 0.f};
    float m = -1e30f, l = 0.f;

    const int srow = tid & 63;
    const int sdg  = tid >> 6;

    bf8 pk0, pk1, pl0, pl1, pv0, pv1;
    if (its < ite) {
        const int t0 = its * 64;
        const unsigned short* kr = khb + (size_t)(t0 + srow) * Dn + sdg * 16;
        const unsigned short* lr = klb + (size_t)(t0 + srow) * Dn + sdg * 16;
        const unsigned short* vr = vTb + (size_t)srow * Sn + t0 + sdg * 16;
        pk0 = *(const bf8*)(kr);  pk1 = *(const bf8*)(kr + 8);
        pl0 = *(const bf8*)(lr);  pl1 = *(const bf8*)(lr + 8);
        pv0 = *(const bf8*)(vr);  pv1 = *(const bf8*)(vr + 8);
    }

    for (int it = its; it < ite; ++it) {
        __syncthreads();
        *(bf8*)&khs[srow][sdg * 16]     = pk0;
        *(bf8*)&khs[srow][sdg * 16 + 8] = pk1;
        *(bf8*)&kls[srow][sdg * 16]     = pl0;
        *(bf8*)&kls[srow][sdg * 16 + 8] = pl1;
        *(bf8*)&vTs[srow][sdg * 16]     = pv0;
        *(bf8*)&vTs[srow][sdg * 16 + 8] = pv1;
        __syncthreads();

        if (it + 1 < ite) {
            const int t1 = (it + 1) * 64;
            const unsigned short* kr = khb + (size_t)(t1 + srow) * Dn + sdg * 16;
            const unsigned short* lr = klb + (size_t)(t1 + srow) * Dn + sdg * 16;
            const unsigned short* vr = vTb + (size_t)srow * Sn + t1 + sdg * 16;
            pk0 = *(const bf8*)(kr);  pk1 = *(const bf8*)(kr + 8);
            pl0 = *(const bf8*)(lr);  pl1 = *(const bf8*)(lr + 8);
            pv0 = *(const bf8*)(vr);  pv1 = *(const bf8*)(vr + 8);
        }

        f32x4 accS[4];
        #pragma unroll
        for (int mi = 0; mi < 4; ++mi) accS[mi] = (f32x4){0.f, 0.f, 0.f, 0.f};
        #pragma unroll
        for (int mi = 0; mi < 4; ++mi) {
            #pragma unroll
            for (int c = 0; c < 2; ++c) {
                bf8 ah = *(const bf8*)&khs[mi * 16 + lq][c * 32 + quad * 8];
                bf8 al = *(const bf8*)&kls[mi * 16 + lq][c * 32 + quad * 8];
                accS[mi] = __builtin_amdgcn_mfma_f32_16x16x32_bf16(ah, qfh[c], accS[mi], 0, 0, 0);
                accS[mi] = __builtin_amdgcn_mfma_f32_16x16x32_bf16(ah, qfl[c], accS[mi], 0, 0, 0);
                accS[mi] = __builtin_amdgcn_mfma_f32_16x16x32_bf16(al, qfh[c], accS[mi], 0, 0, 0);
            }
        }

        if (it == qt) {
            const int qrel = wave * 16 + lq;
            #pragma unroll
            for (int mi = 0; mi < 4; ++mi)
                #pragma unroll
                for (int r = 0; r < 4; ++r)
                    if (mi * 16 + quad * 4 + r > qrel) accS[mi][r] = -INFINITY;
        }

        float mt = -INFINITY;
        #pragma unroll
        for (int mi = 0; mi < 4; ++mi)
            #pragma unroll
            for (int r = 0; r < 4; ++r) mt = fmaxf(mt, accS[mi][r]);
        mt = fmaxf(mt, __shfl_xor(mt, 16));
        mt = fmaxf(mt, __shfl_xor(mt, 32));
        const float mnew = fmaxf(m, mt);
        const float alpha = __expf(m - mnew);
        float ls = 0.f;
        #pragma unroll
        for (int mi = 0; mi < 4; ++mi)
            #pragma unroll
            for (int r = 0; r < 4; ++r) {
                const float p = __expf(accS[mi][r] - mnew);
                accS[mi][r] = p;
                ls += p;
            }
        ls += __shfl_xor(ls, 16);
        ls += __shfl_xor(ls, 32);
        l = l * alpha + ls;
        m = mnew;

        #pragma unroll
        for (int mi = 0; mi < 4; ++mi) {
            ushort4 pk;
            pk.x = f2bf(accS[mi][0]);
            pk.y = f2bf(accS[mi][1]);
            pk.z = f2bf(accS[mi][2]);
            pk.w = f2bf(accS[mi][3]);
            *(ushort4*)&pts[wave * 16 + lq][mi * 16 + quad * 4] = pk;
        }
        if (quad == 0) alf[wave * 16 + lq] = alpha;

        {
            float4 al4 = *(const float4*)&alf[wave * 16 + quad * 4];
            #pragma unroll
            for (int nj = 0; nj < 4; ++nj) {
                accO[nj][0] *= al4.x;
                accO[nj][1] *= al4.y;
                accO[nj][2] *= al4.z;
                accO[nj][3] *= al4.w;
            }
            #pragma unroll
            for (int c = 0; c < 2; ++c) {
                bf8 pf = *(const bf8*)&pts[wave * 16 + lq][c * 32 + quad * 8];
                #pragma unroll
                for (int nj = 0; nj < 4; ++nj) {
                    bf8 vf = *(const bf8*)&vTs[nj * 16 + lq][c * 32 + quad * 8];
                    accO[nj] = __builtin_amdgcn_mfma_f32_16x16x32_bf16(pf, vf, accO[nj], 0, 0, 0);
                }
            }
        }
    }

    if (quad == 0) {
        const size_t mi_ = ((size_t)pslot * 64 + wave * 16 + lq) * 2;
        ml[mi_]     = m;
        ml[mi_ + 1] = l;
    }
    #pragma unroll
    for (int r = 0; r < 4; ++r) {
        const int q = wave * 16 + quad * 4 + r;
        unsigned short* dst = Op + ((size_t)pslot * 64 + q) * 64;
        #pragma unroll
        for (int nj = 0; nj < 4; ++nj)
            dst[nj * 16 + lq] = f2bf(accO[nj][r]);
    }
}

// ---------------------------------------------------------------------------
// Kernel 3 (v5 = R9-exact): fused combine + out-projection + residual,
// split-K=2. Grid (64, 4, 2) = 512 blocks.
// ---------------------------------------------------------------------------
__global__ __launch_bounds__(256)
void out_gemm(const unsigned short* __restrict__ Op,
              const float* __restrict__ ml,
              const unsigned short* __restrict__ Wph,
              const unsigned short* __restrict__ Wpl,
              const float* __restrict__ bp,
              const float* __restrict__ x,
              float* __restrict__ outp,
              float* __restrict__ outp2)
{
    __shared__ unsigned short Ah[64][40], Al[64][40];
    __shared__ unsigned short Bh[128][40], Bl[128][40];

    const int tid = threadIdx.x;
    const int m0 = blockIdx.x * 64;
    const int n0 = blockIdx.y * 128;
    const int kz = blockIdx.z;
    const int kbeg = kz * 256, kend = kbeg + 256;

    const int wave = tid >> 6, lane = tid & 63;
    const int wm = (wave >> 1) * 32, wn = (wave & 1) * 64;
    const int lm = lane & 15, quad = lane >> 4;

    const int am = tid >> 2;
    const int aks = (tid & 3) * 8;
    const int m_row = m0 + am;
    const int b_row = m_row >> 11, s_row = m_row & 2047;
    const int qt = s_row >> 6, qq = s_row & 63;

    // per-head combine scales c0/c1 for this row
    float c0[8], c1[8];
    #pragma unroll
    for (int h = 0; h < 8; ++h) {
        const size_t base0 = (((size_t)(b_row * 8 + h) * 32 + qt) * 64 + qq) * 2;
        const size_t base1 = base0 + (size_t)512 * 64 * 2;
        const float m0_ = ml[base0], l0_ = ml[base0 + 1];
        const float m1_ = ml[base1], l1_ = ml[base1 + 1];
        const float mn = fmaxf(m0_, m1_);
        const float a0 = __expf(m0_ - mn), a1 = __expf(m1_ - mn);
        const float inv = 1.f / (a0 * l0_ + a1 * l1_);
        c0[h] = a0 * inv;
        c1[h] = a1 * inv;
    }

    const int bn = tid >> 1;
    const int bks = (tid & 1) * 16;
    const unsigned short* brh = Wph + (size_t)(n0 + bn) * En + bks;
    const unsigned short* brl = Wpl + (size_t)(n0 + bn) * En + bks;

    f32x4 acc[2][4];
    #pragma unroll
    for (int i = 0; i < 2; ++i)
        #pragma unroll
        for (int j = 0; j < 4; ++j) acc[i][j] = (f32x4){0.f, 0.f, 0.f, 0.f};

    for (int k0 = kbeg; k0 < kend; k0 += 32) {
        {
            const int e0 = k0 + aks;          // 8 elems, single head
            const int h = 7 - (e0 >> 6);
            const int d = e0 & 63;
            const size_t p0 = (((size_t)((b_row * 8 + h) * 32 + qt)) * 64 + qq) * 64 + d;
            const size_t p1 = p0 + (size_t)512 * 64 * 64;
            bf8 o0 = *(const bf8*)(Op + p0);
            bf8 o1 = *(const bf8*)(Op + p1);
            const float w0 = c0[h], w1 = c1[h];
            unsigned short hi[8], lo[8];
            #pragma unroll
            for (int j = 0; j < 8; ++j) {
                const float v = w0 * bf2f((unsigned short)o0[j]) +
                                w1 * bf2f((unsigned short)o1[j]);
                split2(v, hi[j], lo[j]);
            }
            *(bf8*)&Ah[am][aks] = *(bf8*)&hi[0];
            *(bf8*)&Al[am][aks] = *(bf8*)&lo[0];
        }
        *(bf8*)&Bh[bn][bks]     = *(const bf8*)(brh + k0);
        *(bf8*)&Bh[bn][bks + 8] = *(const bf8*)(brh + k0 + 8);
        *(bf8*)&Bl[bn][bks]     = *(const bf8*)(brl + k0);
        *(bf8*)&Bl[bn][bks + 8] = *(const bf8*)(brl + k0 + 8);
        __syncthreads();

        bf8 a_h[2], a_l[2], b_h[4], b_l[4];
        #pragma unroll
        for (int mi = 0; mi < 2; ++mi) {
            a_h[mi] = *(const bf8*)&Ah[wm + mi * 16 + lm][quad * 8];
            a_l[mi] = *(const bf8*)&Al[wm + mi * 16 + lm][quad * 8];
        }
        #pragma unroll
        for (int ni = 0; ni < 4; ++ni) {
            b_h[ni] = *(const bf8*)&Bh[wn + ni * 16 + lm][quad * 8];
            b_l[ni] = *(const bf8*)&Bl[wn + ni * 16 + lm][quad * 8];
        }
        #pragma unroll
        for (int mi = 0; mi < 2; ++mi)
            #pragma unroll
            for (int ni = 0; ni < 4; ++ni) {
                acc[mi][ni] = __builtin_amdgcn_mfma_f32_16x16x32_bf16(a_h[mi], b_h[ni], acc[mi][ni], 0, 0, 0);
                acc[mi][ni] = __builtin_amdgcn_mfma_f32_16x16x32_bf16(a_h[mi], b_l[ni], acc[mi][ni], 0, 0, 0);
                acc[mi][ni] = __builtin_amdgcn_mfma_f32_16x16x32_bf16(a_l[mi], b_h[ni], acc[mi][ni], 0, 0, 0);
            }
        __syncthreads();
    }

    float* dst = kz ? outp2 : outp;
    #pragma unroll
    for (int mi = 0; mi < 2; ++mi) {
        #pragma unroll
        for (int r = 0; r < 4; ++r) {
            const int m = m0 + wm + mi * 16 + quad * 4 + r;
            #pragma unroll
            for (int ni = 0; ni < 4; ++ni) {
                const int n = n0 + wn + ni * 16 + lm;
                const size_t idx = (size_t)m * En + n;
                const float extra = kz ? 0.f : (bp[n] + x[idx]);
                dst[idx] = acc[mi][ni][r] + extra;
            }
        }
    }
}

// ---------------------------------------------------------------------------
// Kernel 4 (v3 = R9-exact): LayerNorm over (outp + outp2), 1 wave per row.
// ---------------------------------------------------------------------------
__global__ __launch_bounds__(256)
void ln_kernel(const float* __restrict__ outp,
               const float* __restrict__ outp2,
               const float* __restrict__ gamma,
               const float* __restrict__ beta,
               float* __restrict__ y)
{
    const int row = blockIdx.x * 4 + (threadIdx.x >> 6);
    const int lane = threadIdx.x & 63;
    const size_t off = (size_t)row * En + lane * 8;

    float a[8], b2[8];
    *(float4*)&a[0] = *(const float4*)(outp + off);
    *(float4*)&a[4] = *(const float4*)(outp + off + 4);
    *(float4*)&b2[0] = *(const float4*)(outp2 + off);
    *(float4*)&b2[4] = *(const float4*)(outp2 + off + 4);
    #pragma unroll
    for (int j = 0; j < 8; ++j) a[j] += b2[j];

    float sum = 0.f, sq = 0.f;
    #pragma unroll
    for (int j = 0; j < 8; ++j) { sum += a[j]; sq += a[j] * a[j]; }
    #pragma unroll
    for (int off_ = 1; off_ < 64; off_ <<= 1) {
        sum += __shfl_xor(sum, off_);
        sq  += __shfl_xor(sq, off_);
    }
    const float mu = sum * (1.f / 512.f);
    const float var = sq * (1.f / 512.f) - mu * mu;
    const float rs = rsqrtf(var + 1e-5f);

    const float* g = gamma + lane * 8;
    const float* be = beta + lane * 8;
    float o[8];
    #pragma unroll
    for (int j = 0; j < 8; ++j)
        o[j] = (a[j] - mu) * rs * g[j] + be[j];
    float* yr = y + off;
    *(float4*)(yr)     = *(float4*)&o[0];
    *(float4*)(yr + 4) = *(float4*)&o[4];
}

// ---------------------------------------------------------------------------
extern "C" void kernel_launch(void* const* d_in, const int* in_sizes, int n_in,
                              void* d_out, int out_size, void* d_ws, size_t ws_size,
                              hipStream_t stream)
{
    const float* x     = (const float*)d_in[0];
    const float* Wq    = (const float*)d_in[1];
    const float* Wk    = (const float*)d_in[2];
    const float* Wv    = (const float*)d_in[3];
    const float* Wp    = (const float*)d_in[4];
    const float* bp    = (const float*)d_in[5];
    const float* gamma = (const float*)d_in[6];
    const float* beta  = (const float*)d_in[7];
    // d_in[8] = mask (int32 tril) — causal, applied analytically.

    float* ws   = (float*)d_ws;
    float* ml   = ws;                            // 131,072 floats
    float* outp = ws + XY;                       // 2M floats (8 MB)
    unsigned short* bfb = (unsigned short*)(ws + 2 * XY);
    unsigned short* xh  = bfb;
    unsigned short* xl  = bfb + XY;
    unsigned short* Wth = bfb + 2 * XY;
    unsigned short* Wtl = Wth + WT;
    unsigned short* Wph = Wtl + WT;
    unsigned short* Wpl = Wph + WP;
    unsigned short* qh  = Wpl + WP;
    unsigned short* ql  = qh + PL;
    unsigned short* kh  = ql + PL;
    unsigned short* kl  = kh + PL;
    unsigned short* vT  = kl + PL;
    unsigned short* Op = xh;                     // reuse (dead after qkv_gemm)
    float* outp2 = (float*)qh;                   // reuse (dead after attn)

    const int attn_lds = 18432 * 2 + 256;        // 37,120 B
    hipFuncSetAttribute((const void*)attn,
                        hipFuncAttributeMaxDynamicSharedMemorySize, attn_lds);

    prep<<<dim3(1344), 256, 0, stream>>>(x, Wp, Wq, Wk, Wv,
                                         xh, xl, Wph, Wpl, Wth, Wtl);
    qkv_gemm<<<dim3(12, Mn / 128), 512, 0, stream>>>(xh, xl, Wth, Wtl,
                                                     qh, ql, kh, kl, vT);
    attn<<<dim3(1024), 256, attn_lds, stream>>>(qh, ql, kh, kl, vT, Op, ml);
    out_gemm<<<dim3(Mn / 64, En / 128, 2), 256, 0, stream>>>(Op, ml, Wph, Wpl,
                                                             bp, x, outp, outp2);
    ln_kernel<<<dim3(Mn / 4), 256, 0, stream>>>(outp, outp2, gamma, beta,
                                                (float*)d_out);
}

// Round 13
// 177.532 us; speedup vs baseline: 1.0424x; 1.0299x over previous
//
#include <hip/hip_runtime.h>

// Problem constants
constexpr int Bn = 2;
constexpr int Sn = 2048;
constexpr int En = 512;
constexpr int Hn = 8;
constexpr int Dn = 64;
constexpr int Mn = Bn * Sn;              // 4096 rows

typedef short bf8 __attribute__((ext_vector_type(8)));
typedef float f32x4 __attribute__((ext_vector_type(4)));

// element counts (ushort units) for the bf16 workspace region
constexpr size_t XY = (size_t)Mn * En;          // 2,097,152  x planes
constexpr size_t WT = (size_t)3 * En * En;      //   786,432  Wqkv transposed planes
constexpr size_t WP = (size_t)En * En;          //   262,144  Wp planes
constexpr size_t PL = (size_t)Bn * Hn * Sn * Dn;// 2,097,152  q/k/v planes

__device__ __forceinline__ unsigned short f2bf(float f) {
    unsigned int u = __float_as_uint(f);
    unsigned int r = 0x7FFFu + ((u >> 16) & 1u);
    return (unsigned short)((u + r) >> 16);
}
__device__ __forceinline__ float bf2f(unsigned short u) {
    return __uint_as_float(((unsigned int)u) << 16);
}
__device__ __forceinline__ void split2(float f, unsigned short& hi, unsigned short& lo) {
    hi = f2bf(f);
    lo = f2bf(f - bf2f(hi));
}

// ---------------------------------------------------------------------------
// Prep (fused): blocks [0,1024) presplit x; [1024,1152) presplit Wp;
// [1152,1344) transpose+split Wq/Wk/Wv -> Wt[n][k]. (R9-exact)
// ---------------------------------------------------------------------------
__global__ __launch_bounds__(256)
void prep(const float* __restrict__ x, const float* __restrict__ Wp,
          const float* __restrict__ Wq, const float* __restrict__ Wk,
          const float* __restrict__ Wv,
          unsigned short* __restrict__ xh, unsigned short* __restrict__ xl,
          unsigned short* __restrict__ Wph, unsigned short* __restrict__ Wpl,
          unsigned short* __restrict__ Wth, unsigned short* __restrict__ Wtl)
{
    __shared__ float t[64][65];
    const int bid = blockIdx.x;
    const int tid = threadIdx.x;

    if (bid < 1152) {
        const float* src = (bid < 1024) ? x : Wp;
        unsigned short* hp = (bid < 1024) ? xh : Wph;
        unsigned short* lp = (bid < 1024) ? xl : Wpl;
        const int blk = (bid < 1024) ? bid : (bid - 1024);
        const size_t base = ((size_t)blk * 256 + tid) * 8;
        float a[8];
        *(float4*)&a[0] = *(const float4*)(src + base);
        *(float4*)&a[4] = *(const float4*)(src + base + 4);
        unsigned short h[8], l[8];
        #pragma unroll
        for (int j = 0; j < 8; ++j) split2(a[j], h[j], l[j]);
        *(bf8*)(hp + base) = *(bf8*)&h[0];
        *(bf8*)(lp + base) = *(bf8*)&l[0];
        return;
    }

    const int idx = bid - 1152;           // 0..191
    const int ph = idx >> 3;              // 0..23
    const int proj = ph >> 3, h = ph & 7;
    const int e0 = (idx & 7) * 64;
    const float* W = (proj == 0) ? Wq : (proj == 1) ? Wk : Wv;
    const float* src = W + (size_t)h * En * Dn + (size_t)e0 * Dn;

    const int er = tid >> 2, cg = (tid & 3) * 16;
    #pragma unroll
    for (int c = 0; c < 4; ++c) {
        float4 v = *(const float4*)(src + (size_t)er * Dn + cg + 4 * c);
        t[er][cg + 4 * c + 0] = v.x;
        t[er][cg + 4 * c + 1] = v.y;
        t[er][cg + 4 * c + 2] = v.z;
        t[er][cg + 4 * c + 3] = v.w;
    }
    __syncthreads();

    const int d = tid >> 2, jg = (tid & 3) * 16;
    unsigned short h16[16], l16[16];
    #pragma unroll
    for (int j = 0; j < 16; ++j) split2(t[jg + j][d], h16[j], l16[j]);
    const size_t n = (size_t)proj * 512 + h * 64 + d;
    unsigned short* dh = Wth + n * En + e0 + jg;
    unsigned short* dl = Wtl + n * En + e0 + jg;
    *(bf8*)dh       = *(bf8*)&h16[0];
    *(bf8*)(dh + 8) = *(bf8*)&h16[8];
    *(bf8*)dl       = *(bf8*)&l16[0];
    *(bf8*)(dl + 8) = *(bf8*)&l16[8];
}

// ---------------------------------------------------------------------------
// Kernel 1 (R9-exact): fused QKV projection, 128x64 tiles (one head per
// block). Grid (32, 24) = 768 blocks -> 3 blocks/CU. LDS 30,720 B.
// ---------------------------------------------------------------------------
__global__ __launch_bounds__(256)
void qkv_gemm(const unsigned short* __restrict__ xh,
              const unsigned short* __restrict__ xl,
              const unsigned short* __restrict__ Wth,
              const unsigned short* __restrict__ Wtl,
              unsigned short* __restrict__ qh_g,
              unsigned short* __restrict__ ql_g,
              unsigned short* __restrict__ kh_g,
              unsigned short* __restrict__ kl_g,
              unsigned short* __restrict__ vT_g)
{
    __shared__ __align__(16) unsigned char smraw[30720];
    unsigned short (*Ah)[40] = (unsigned short(*)[40])(smraw);          // 128 x 40
    unsigned short (*Al)[40] = (unsigned short(*)[40])(smraw + 10240);
    unsigned short (*Bh)[40] = (unsigned short(*)[40])(smraw + 20480);  // 64 x 40
    unsigned short (*Bl)[40] = (unsigned short(*)[40])(smraw + 25600);
    float (*Cf)[68] = (float(*)[68])(smraw);    // 64 x 68 fp32 = 17,408 B

    const int tid = threadIdx.x;
    const int m0 = blockIdx.x * 128;
    const int ny = blockIdx.y;            // 0..23
    const int proj = ny >> 3, h = ny & 7;

    const int wave = tid >> 6, lane = tid & 63;
    const int wm = (wave >> 1) * 64, wn = (wave & 1) * 32;
    const int lm = lane & 15, quad = lane >> 4;

    const int am = tid >> 1;              // 0..127
    const int aks = (tid & 1) * 16;
    const unsigned short* arh = xh + (size_t)(m0 + am) * En + aks;
    const unsigned short* arl = xl + (size_t)(m0 + am) * En + aks;

    const int bn = tid >> 2;              // 0..63
    const int bks = (tid & 3) * 8;
    const unsigned short* brh = Wth + (size_t)(ny * 64 + bn) * En + bks;
    const unsigned short* brl = Wtl + (size_t)(ny * 64 + bn) * En + bks;

    f32x4 acc[4][2];
    #pragma unroll
    for (int i = 0; i < 4; ++i)
        #pragma unroll
        for (int j = 0; j < 2; ++j) acc[i][j] = (f32x4){0.f, 0.f, 0.f, 0.f};

    for (int k0 = 0; k0 < En; k0 += 32) {
        *(bf8*)&Ah[am][aks]     = *(const bf8*)(arh + k0);
        *(bf8*)&Ah[am][aks + 8] = *(const bf8*)(arh + k0 + 8);
        *(bf8*)&Al[am][aks]     = *(const bf8*)(arl + k0);
        *(bf8*)&Al[am][aks + 8] = *(const bf8*)(arl + k0 + 8);
        *(bf8*)&Bh[bn][bks]     = *(const bf8*)(brh + k0);
        *(bf8*)&Bl[bn][bks]     = *(const bf8*)(brl + k0);
        __syncthreads();

        bf8 a_h[4], a_l[4], b_h[2], b_l[2];
        #pragma unroll
        for (int mi = 0; mi < 4; ++mi) {
            a_h[mi] = *(const bf8*)&Ah[wm + mi * 16 + lm][quad * 8];
            a_l[mi] = *(const bf8*)&Al[wm + mi * 16 + lm][quad * 8];
        }
        #pragma unroll
        for (int ni = 0; ni < 2; ++ni) {
            b_h[ni] = *(const bf8*)&Bh[wn + ni * 16 + lm][quad * 8];
            b_l[ni] = *(const bf8*)&Bl[wn + ni * 16 + lm][quad * 8];
        }
        #pragma unroll
        for (int mi = 0; mi < 4; ++mi)
            #pragma unroll
            for (int ni = 0; ni < 2; ++ni) {
                acc[mi][ni] = __builtin_amdgcn_mfma_f32_16x16x32_bf16(a_h[mi], b_h[ni], acc[mi][ni], 0, 0, 0);
                acc[mi][ni] = __builtin_amdgcn_mfma_f32_16x16x32_bf16(a_h[mi], b_l[ni], acc[mi][ni], 0, 0, 0);
                acc[mi][ni] = __builtin_amdgcn_mfma_f32_16x16x32_bf16(a_l[mi], b_h[ni], acc[mi][ni], 0, 0, 0);
            }
        __syncthreads();
    }

    if (proj < 2) {
        unsigned short* hp = (proj == 0) ? qh_g : kh_g;
        unsigned short* lp = (proj == 0) ? ql_g : kl_g;
        #pragma unroll
        for (int p = 0; p < 2; ++p) {
            if ((wave >> 1) == p) {
                #pragma unroll
                for (int mi = 0; mi < 4; ++mi)
                    #pragma unroll
                    for (int ni = 0; ni < 2; ++ni)
                        #pragma unroll
                        for (int r = 0; r < 4; ++r)
                            Cf[mi * 16 + quad * 4 + r][wn + ni * 16 + lm] = acc[mi][ni][r];
            }
            __syncthreads();
            {
                const int lr = tid & 63;
                const int cg = (tid >> 6) * 16;   // wave-uniform d-chunk
                const int m = m0 + p * 64 + lr;
                const int b = m >> 11, s = m & 2047;
                unsigned short hi[16], lo[16];
                #pragma unroll
                for (int j4 = 0; j4 < 4; ++j4) {
                    float4 v = *(const float4*)&Cf[lr][cg + 4 * j4];
                    split2(v.x, hi[4 * j4 + 0], lo[4 * j4 + 0]);
                    split2(v.y, hi[4 * j4 + 1], lo[4 * j4 + 1]);
                    split2(v.z, hi[4 * j4 + 2], lo[4 * j4 + 2]);
                    split2(v.w, hi[4 * j4 + 3], lo[4 * j4 + 3]);
                }
                const size_t base = (((size_t)(b * Hn + h) * Sn + s) * Dn) + cg;
                *(bf8*)(hp + base)     = *(bf8*)&hi[0];
                *(bf8*)(hp + base + 8) = *(bf8*)&hi[8];
                *(bf8*)(lp + base)     = *(bf8*)&lo[0];
                *(bf8*)(lp + base + 8) = *(bf8*)&lo[8];
            }
            __syncthreads();
        }
    } else {
        #pragma unroll
        for (int mi = 0; mi < 4; ++mi) {
            const int s0 = m0 + wm + mi * 16 + quad * 4;
            const int b = s0 >> 11, s = s0 & 2047;
            #pragma unroll
            for (int ni = 0; ni < 2; ++ni) {
                const int d = wn + ni * 16 + lm;
                ushort4 pk;
                pk.x = f2bf(acc[mi][ni][0]);
                pk.y = f2bf(acc[mi][ni][1]);
                pk.z = f2bf(acc[mi][ni][2]);
                pk.w = f2bf(acc[mi][ni][3]);
                *(ushort4*)(vT_g + ((size_t)(b * Hn + h) * Dn + d) * Sn + s) = pk;
            }
        }
    }
}

// ---------------------------------------------------------------------------
// Kernel 2 (v7): MFMA flash attention, 2-way split-t, XCD-aware bh mapping.
// bid = g*8 + xcd; bh = 2*xcd + (g&1) -> all 64 blocks sharing a bh land on
// one XCD; 2 bh x 1.5 MB K/V = 3 MB <= 4 MB per-XCD L2 (local L2 hits).
// Arithmetic / pslot layout identical to R9.
// ---------------------------------------------------------------------------
__global__ __launch_bounds__(256)
void attn(const unsigned short* __restrict__ qh_g,
          const unsigned short* __restrict__ ql_g,
          const unsigned short* __restrict__ kh_g,
          const unsigned short* __restrict__ kl_g,
          const unsigned short* __restrict__ vT_g,
          unsigned short* __restrict__ Op,
          float* __restrict__ ml)
{
    extern __shared__ unsigned short sm[];
    unsigned short (*khs)[72] = (unsigned short(*)[72])(sm);          // [t][d] hi
    unsigned short (*kls)[72] = (unsigned short(*)[72])(sm + 4608);   // [t][d] lo
    unsigned short (*vTs)[72] = (unsigned short(*)[72])(sm + 9216);   // [d][t]
    unsigned short (*pts)[72] = (unsigned short(*)[72])(sm + 13824);  // [q][t]
    float* alf = (float*)(sm + 18432);                                // [64]

    const int bidx = blockIdx.x;
    const int xcd = bidx & 7;
    const int g = bidx >> 3;              // 0..127
    const int bh = xcd * 2 + (g & 1);     // 2 bh per XCD
    const int rest = g >> 1;              // 0..63
    const int hf = rest >> 5;             // K-range half
    const int a_ = rest & 31;
    const int qt = hf ? (31 - a_) : a_;   // direction alternation for balance
    const int n0 = (qt + 2) >> 1;
    const int its = hf ? n0 : 0;
    const int ite = hf ? (qt + 1) : n0;
    const int pslot = hf * 512 + bh * 32 + qt;

    const int tid = threadIdx.x;
    const int wave = tid >> 6, lane = tid & 63;
    const int quad = lane >> 4, lq = lane & 15;

    const unsigned short* khb = kh_g + (size_t)bh * Sn * Dn;
    const unsigned short* klb = kl_g + (size_t)bh * Sn * Dn;
    const unsigned short* vTb = vT_g + (size_t)bh * Dn * Sn;

    bf8 qfh[2], qfl[2];
    {
        const size_t qoff = ((size_t)bh * Sn + (size_t)qt * 64 + wave * 16 + lq) * Dn;
        #pragma unroll
        for (int c = 0; c < 2; ++c) {
            qfh[c] = *(const bf8*)(qh_g + qoff + c * 32 + quad * 8);
            qfl[c] = *(const bf8*)(ql_g + qoff + c * 32 + quad * 8);
        }
    }

    f32x4 accO[4];
    #pragma unroll
    for (int nj = 0; nj < 4; ++nj) accO[nj] = (f32x4){0.f, 0.f, 0.f, 0.f};
    float m = -1e30f, l = 0.f;

    const int srow = tid & 63;
    const int sdg  = tid >> 6;

    bf8 pk0, pk1, pl0, pl1, pv0, pv1;
    if (its < ite) {
        const int t0 = its * 64;
        const unsigned short* kr = khb + (size_t)(t0 + srow) * Dn + sdg * 16;
        const unsigned short* lr = klb + (size_t)(t0 + srow) * Dn + sdg * 16;
        const unsigned short* vr = vTb + (size_t)srow * Sn + t0 + sdg * 16;
        pk0 = *(const bf8*)(kr);  pk1 = *(const bf8*)(kr + 8);
        pl0 = *(const bf8*)(lr);  pl1 = *(const bf8*)(lr + 8);
        pv0 = *(const bf8*)(vr);  pv1 = *(const bf8*)(vr + 8);
    }

    for (int it = its; it < ite; ++it) {
        __syncthreads();
        *(bf8*)&khs[srow][sdg * 16]     = pk0;
        *(bf8*)&khs[srow][sdg * 16 + 8] = pk1;
        *(bf8*)&kls[srow][sdg * 16]     = pl0;
        *(bf8*)&kls[srow][sdg * 16 + 8] = pl1;
        *(bf8*)&vTs[srow][sdg * 16]     = pv0;
        *(bf8*)&vTs[srow][sdg * 16 + 8] = pv1;
        __syncthreads();

        if (it + 1 < ite) {
            const int t1 = (it + 1) * 64;
            const unsigned short* kr = khb + (size_t)(t1 + srow) * Dn + sdg * 16;
            const unsigned short* lr = klb + (size_t)(t1 + srow) * Dn + sdg * 16;
            const unsigned short* vr = vTb + (size_t)srow * Sn + t1 + sdg * 16;
            pk0 = *(const bf8*)(kr);  pk1 = *(const bf8*)(kr + 8);
            pl0 = *(const bf8*)(lr);  pl1 = *(const bf8*)(lr + 8);
            pv0 = *(const bf8*)(vr);  pv1 = *(const bf8*)(vr + 8);
        }

        f32x4 accS[4];
        #pragma unroll
        for (int mi = 0; mi < 4; ++mi) accS[mi] = (f32x4){0.f, 0.f, 0.f, 0.f};
        #pragma unroll
        for (int mi = 0; mi < 4; ++mi) {
            #pragma unroll
            for (int c = 0; c < 2; ++c) {
                bf8 ah = *(const bf8*)&khs[mi * 16 + lq][c * 32 + quad * 8];
                bf8 al = *(const bf8*)&kls[mi * 16 + lq][c * 32 + quad * 8];
                accS[mi] = __builtin_amdgcn_mfma_f32_16x16x32_bf16(ah, qfh[c], accS[mi], 0, 0, 0);
                accS[mi] = __builtin_amdgcn_mfma_f32_16x16x32_bf16(ah, qfl[c], accS[mi], 0, 0, 0);
                accS[mi] = __builtin_amdgcn_mfma_f32_16x16x32_bf16(al, qfh[c], accS[mi], 0, 0, 0);
            }
        }

        if (it == qt) {
            const int qrel = wave * 16 + lq;
            #pragma unroll
            for (int mi = 0; mi < 4; ++mi)
                #pragma unroll
                for (int r = 0; r < 4; ++r)
                    if (mi * 16 + quad * 4 + r > qrel) accS[mi][r] = -INFINITY;
        }

        float mt = -INFINITY;
        #pragma unroll
        for (int mi = 0; mi < 4; ++mi)
            #pragma unroll
            for (int r = 0; r < 4; ++r) mt = fmaxf(mt, accS[mi][r]);
        mt = fmaxf(mt, __shfl_xor(mt, 16));
        mt = fmaxf(mt, __shfl_xor(mt, 32));
        const float mnew = fmaxf(m, mt);
        const float alpha = __expf(m - mnew);
        float ls = 0.f;
        #pragma unroll
        for (int mi = 0; mi < 4; ++mi)
            #pragma unroll
            for (int r = 0; r < 4; ++r) {
                const float p = __expf(accS[mi][r] - mnew);
                accS[mi][r] = p;
                ls += p;
            }
        ls += __shfl_xor(ls, 16);
        ls += __shfl_xor(ls, 32);
        l = l * alpha + ls;
        m = mnew;

        #pragma unroll
        for (int mi = 0; mi < 4; ++mi) {
            ushort4 pk;
            pk.x = f2bf(accS[mi][0]);
            pk.y = f2bf(accS[mi][1]);
            pk.z = f2bf(accS[mi][2]);
            pk.w = f2bf(accS[mi][3]);
            *(ushort4*)&pts[wave * 16 + lq][mi * 16 + quad * 4] = pk;
        }
        if (quad == 0) alf[wave * 16 + lq] = alpha;

        {
            float4 al4 = *(const float4*)&alf[wave * 16 + quad * 4];
            #pragma unroll
            for (int nj = 0; nj < 4; ++nj) {
                accO[nj][0] *= al4.x;
                accO[nj][1] *= al4.y;
                accO[nj][2] *= al4.z;
                accO[nj][3] *= al4.w;
            }
            #pragma unroll
            for (int c = 0; c < 2; ++c) {
                bf8 pf = *(const bf8*)&pts[wave * 16 + lq][c * 32 + quad * 8];
                #pragma unroll
                for (int nj = 0; nj < 4; ++nj) {
                    bf8 vf = *(const bf8*)&vTs[nj * 16 + lq][c * 32 + quad * 8];
                    accO[nj] = __builtin_amdgcn_mfma_f32_16x16x32_bf16(pf, vf, accO[nj], 0, 0, 0);
                }
            }
        }
    }

    if (quad == 0) {
        const size_t mi_ = ((size_t)pslot * 64 + wave * 16 + lq) * 2;
        ml[mi_]     = m;
        ml[mi_ + 1] = l;
    }
    #pragma unroll
    for (int r = 0; r < 4; ++r) {
        const int q = wave * 16 + quad * 4 + r;
        unsigned short* dst = Op + ((size_t)pslot * 64 + q) * 64;
        #pragma unroll
        for (int nj = 0; nj < 4; ++nj)
            dst[nj * 16 + lq] = f2bf(accO[nj][r]);
    }
}

// ---------------------------------------------------------------------------
// Kernel 3 (R9-exact): fused combine + out-projection + residual, split-K=2.
// Grid (64, 4, 2) = 512 blocks (2/CU).
// ---------------------------------------------------------------------------
__global__ __launch_bounds__(256)
void out_gemm(const unsigned short* __restrict__ Op,
              const float* __restrict__ ml,
              const unsigned short* __restrict__ Wph,
              const unsigned short* __restrict__ Wpl,
              const float* __restrict__ bp,
              const float* __restrict__ x,
              float* __restrict__ outp,
              float* __restrict__ outp2)
{
    __shared__ unsigned short Ah[64][40], Al[64][40];
    __shared__ unsigned short Bh[128][40], Bl[128][40];

    const int tid = threadIdx.x;
    const int m0 = blockIdx.x * 64;
    const int n0 = blockIdx.y * 128;
    const int kz = blockIdx.z;
    const int kbeg = kz * 256, kend = kbeg + 256;

    const int wave = tid >> 6, lane = tid & 63;
    const int wm = (wave >> 1) * 32, wn = (wave & 1) * 64;
    const int lm = lane & 15, quad = lane >> 4;

    const int am = tid >> 2;
    const int aks = (tid & 3) * 8;
    const int m_row = m0 + am;
    const int b_row = m_row >> 11, s_row = m_row & 2047;
    const int qt = s_row >> 6, qq = s_row & 63;

    // per-head combine scales c0/c1 for this row
    float c0[8], c1[8];
    #pragma unroll
    for (int h = 0; h < 8; ++h) {
        const size_t base0 = (((size_t)(b_row * 8 + h) * 32 + qt) * 64 + qq) * 2;
        const size_t base1 = base0 + (size_t)512 * 64 * 2;
        const float m0_ = ml[base0], l0_ = ml[base0 + 1];
        const float m1_ = ml[base1], l1_ = ml[base1 + 1];
        const float mn = fmaxf(m0_, m1_);
        const float a0 = __expf(m0_ - mn), a1 = __expf(m1_ - mn);
        const float inv = 1.f / (a0 * l0_ + a1 * l1_);
        c0[h] = a0 * inv;
        c1[h] = a1 * inv;
    }

    const int bn = tid >> 1;
    const int bks = (tid & 1) * 16;
    const unsigned short* brh = Wph + (size_t)(n0 + bn) * En + bks;
    const unsigned short* brl = Wpl + (size_t)(n0 + bn) * En + bks;

    f32x4 acc[2][4];
    #pragma unroll
    for (int i = 0; i < 2; ++i)
        #pragma unroll
        for (int j = 0; j < 4; ++j) acc[i][j] = (f32x4){0.f, 0.f, 0.f, 0.f};

    for (int k0 = kbeg; k0 < kend; k0 += 32) {
        {
            const int e0 = k0 + aks;          // 8 elems, single head
            const int h = 7 - (e0 >> 6);
            const int d = e0 & 63;
            const size_t p0 = (((size_t)((b_row * 8 + h) * 32 + qt)) * 64 + qq) * 64 + d;
            const size_t p1 = p0 + (size_t)512 * 64 * 64;
            bf8 o0 = *(const bf8*)(Op + p0);
            bf8 o1 = *(const bf8*)(Op + p1);
            const float w0 = c0[h], w1 = c1[h];
            unsigned short hi[8], lo[8];
            #pragma unroll
            for (int j = 0; j < 8; ++j) {
                const float v = w0 * bf2f((unsigned short)o0[j]) +
                                w1 * bf2f((unsigned short)o1[j]);
                split2(v, hi[j], lo[j]);
            }
            *(bf8*)&Ah[am][aks] = *(bf8*)&hi[0];
            *(bf8*)&Al[am][aks] = *(bf8*)&lo[0];
        }
        *(bf8*)&Bh[bn][bks]     = *(const bf8*)(brh + k0);
        *(bf8*)&Bh[bn][bks + 8] = *(const bf8*)(brh + k0 + 8);
        *(bf8*)&Bl[bn][bks]     = *(const bf8*)(brl + k0);
        *(bf8*)&Bl[bn][bks + 8] = *(const bf8*)(brl + k0 + 8);
        __syncthreads();

        bf8 a_h[2], a_l[2], b_h[4], b_l[4];
        #pragma unroll
        for (int mi = 0; mi < 2; ++mi) {
            a_h[mi] = *(const bf8*)&Ah[wm + mi * 16 + lm][quad * 8];
            a_l[mi] = *(const bf8*)&Al[wm + mi * 16 + lm][quad * 8];
        }
        #pragma unroll
        for (int ni = 0; ni < 4; ++ni) {
            b_h[ni] = *(const bf8*)&Bh[wn + ni * 16 + lm][quad * 8];
            b_l[ni] = *(const bf8*)&Bl[wn + ni * 16 + lm][quad * 8];
        }
        #pragma unroll
        for (int mi = 0; mi < 2; ++mi)
            #pragma unroll
            for (int ni = 0; ni < 4; ++ni) {
                acc[mi][ni] = __builtin_amdgcn_mfma_f32_16x16x32_bf16(a_h[mi], b_h[ni], acc[mi][ni], 0, 0, 0);
                acc[mi][ni] = __builtin_amdgcn_mfma_f32_16x16x32_bf16(a_h[mi], b_l[ni], acc[mi][ni], 0, 0, 0);
                acc[mi][ni] = __builtin_amdgcn_mfma_f32_16x16x32_bf16(a_l[mi], b_h[ni], acc[mi][ni], 0, 0, 0);
            }
        __syncthreads();
    }

    float* dst = kz ? outp2 : outp;
    #pragma unroll
    for (int mi = 0; mi < 2; ++mi) {
        #pragma unroll
        for (int r = 0; r < 4; ++r) {
            const int m = m0 + wm + mi * 16 + quad * 4 + r;
            #pragma unroll
            for (int ni = 0; ni < 4; ++ni) {
                const int n = n0 + wn + ni * 16 + lm;
                const size_t idx = (size_t)m * En + n;
                const float extra = kz ? 0.f : (bp[n] + x[idx]);
                dst[idx] = acc[mi][ni][r] + extra;
            }
        }
    }
}

// ---------------------------------------------------------------------------
// Kernel 4 (R9-exact): LayerNorm over (outp + outp2), 1 wave per row.
// ---------------------------------------------------------------------------
__global__ __launch_bounds__(256)
void ln_kernel(const float* __restrict__ outp,
               const float* __restrict__ outp2,
               const float* __restrict__ gamma,
               const float* __restrict__ beta,
               float* __restrict__ y)
{
    const int row = blockIdx.x * 4 + (threadIdx.x >> 6);
    const int lane = threadIdx.x & 63;
    const size_t off = (size_t)row * En + lane * 8;

    float a[8], b2[8];
    *(float4*)&a[0] = *(const float4*)(outp + off);
    *(float4*)&a[4] = *(const float4*)(outp + off + 4);
    *(float4*)&b2[0] = *(const float4*)(outp2 + off);
    *(float4*)&b2[4] = *(const float4*)(outp2 + off + 4);
    #pragma unroll
    for (int j = 0; j < 8; ++j) a[j] += b2[j];

    float sum = 0.f, sq = 0.f;
    #pragma unroll
    for (int j = 0; j < 8; ++j) { sum += a[j]; sq += a[j] * a[j]; }
    #pragma unroll
    for (int off_ = 1; off_ < 64; off_ <<= 1) {
        sum += __shfl_xor(sum, off_);
        sq  += __shfl_xor(sq, off_);
    }
    const float mu = sum * (1.f / 512.f);
    const float var = sq * (1.f / 512.f) - mu * mu;
    const float rs = rsqrtf(var + 1e-5f);

    const float* g = gamma + lane * 8;
    const float* be = beta + lane * 8;
    float o[8];
    #pragma unroll
    for (int j = 0; j < 8; ++j)
        o[j] = (a[j] - mu) * rs * g[j] + be[j];
    float* yr = y + off;
    *(float4*)(yr)     = *(float4*)&o[0];
    *(float4*)(yr + 4) = *(float4*)&o[4];
}

// ---------------------------------------------------------------------------
extern "C" void kernel_launch(void* const* d_in, const int* in_sizes, int n_in,
                              void* d_out, int out_size, void* d_ws, size_t ws_size,
                              hipStream_t stream)
{
    const float* x     = (const float*)d_in[0];
    const float* Wq    = (const float*)d_in[1];
    const float* Wk    = (const float*)d_in[2];
    const float* Wv    = (const float*)d_in[3];
    const float* Wp    = (const float*)d_in[4];
    const float* bp    = (const float*)d_in[5];
    const float* gamma = (const float*)d_in[6];
    const float* beta  = (const float*)d_in[7];
    // d_in[8] = mask (int32 tril) — causal, applied analytically.

    float* ws   = (float*)d_ws;
    float* ml   = ws;                            // 131,072 floats
    float* outp = ws + XY;                       // 2M floats (8 MB)
    unsigned short* bfb = (unsigned short*)(ws + 2 * XY);
    unsigned short* xh  = bfb;
    unsigned short* xl  = bfb + XY;
    unsigned short* Wth = bfb + 2 * XY;
    unsigned short* Wtl = Wth + WT;
    unsigned short* Wph = Wtl + WT;
    unsigned short* Wpl = Wph + WP;
    unsigned short* qh  = Wpl + WP;
    unsigned short* ql  = qh + PL;
    unsigned short* kh  = ql + PL;
    unsigned short* kl  = kh + PL;
    unsigned short* vT  = kl + PL;
    unsigned short* Op = xh;                     // reuse (dead after qkv_gemm)
    float* outp2 = (float*)qh;                   // reuse (dead after attn)

    const int attn_lds = 18432 * 2 + 256;        // 37,120 B
    hipFuncSetAttribute((const void*)attn,
                        hipFuncAttributeMaxDynamicSharedMemorySize, attn_lds);

    prep<<<dim3(1344), 256, 0, stream>>>(x, Wp, Wq, Wk, Wv,
                                         xh, xl, Wph, Wpl, Wth, Wtl);
    qkv_gemm<<<dim3(Mn / 128, 24), 256, 0, stream>>>(xh, xl, Wth, Wtl,
                                                     qh, ql, kh, kl, vT);
    attn<<<dim3(1024), 256, attn_lds, stream>>>(qh, ql, kh, kl, vT, Op, ml);
    out_gemm<<<dim3(Mn / 64, En / 128, 2), 256, 0, stream>>>(Op, ml, Wph, Wpl,
                                                             bp, x, outp, outp2);
    ln_kernel<<<dim3(Mn / 4), 256, 0, stream>>>(outp, outp2, gamma, beta,
                                                (float*)d_out);
}